// Round 5
// baseline (362.960 us; speedup 1.0000x reference)
//
#include <hip/hip_runtime.h>

#define HH 512
#define WW 512
#define NIMG 12
#define RAD 3
#define TW 64
#define TH 16
#define LW (TW + 2*RAD)   // 70
#define LH (TH + 2*RAD)   // 22
#define RPW 4             // output rows per wave (TH / 4 waves)

typedef float v2 __attribute__((ext_vector_type(2)));

// R5: streaming-window rewrite for occupancy.
//
// SESSION LEDGER:
//  R1 fuse2 48KB LDS: 256us. Occ 18.6, busy 55 -> latency-bound.
//  R2 fuse2 + bounds(256,4): 554us. VGPR clamp 64 < ring's ~90 -> scratch
//     spill (WRITE 380MB/disp). launch_bounds arg2 is a VGPR clamp first.
//  R3 fuse2 TH=16: 276us. VGPR tier pins 4 waves/SIMD regardless of LDS.
//  R4 unfused + pi-pair ring: 225.5us (best). Gain only ~4% -> conclusion:
//     v_pk_fma_f32 is HALF instruction rate on gfx950 (FP32 peak 157.3TF
//     has no packed doubling); packing removes movs, not fma time. Wall =
//     ~55% VALU issue + ~45% stall at 4-5 waves/SIMD (VGPR 92).
//  R5: stream the 7x7 window one row at a time -> live set ~45 regs ->
//     clamp 64 via bounds(256,8) -> 8 waves/SIMD. ds_reads 2.8x (LDS pipe
//     has headroom); numerics bit-identical (same taps, same order).
//
// NUMERICS CONTRACT (unchanged; harness-validated R1-R4, absmax 9.77e-4):
//  - conv = sequential fma over the 7x7 window, (ky,kx) row-major, one
//    accumulator per direction; im path bit-exact vs the fp32 ref replay.
//  - Streaming preserves every chain's tap order exactly:
//      L/R: rows 0..6, pairs {w[d],w[d+3]} d=0..3     (packed lanes L,R)
//      U:   rows 0..3, cols 0..6 scalar               D: rows 3..6
//      NW/NE: rows 0..3, same pairs (packed)          SW/SE: rows 3..6
//  - pert quadrant decomposition: identical pairwise trees, built from
//    streamed partials: qN=(h0+h1)+(h2+h3) via qn01=h0; qn01+=h1; ... etc.
__global__ __launch_bounds__(256, 8) void swf_step(
    const float* __restrict__ im_in, const float* __restrict__ pe_in,
    float* __restrict__ im_out, float* __restrict__ pe_out, int storeIm)
{
    __shared__ float sI[LH][LW];
    __shared__ float sP[LH][LW];

    const int tid = threadIdx.x;
    const int tx = tid & 63;
    const int wv = tid >> 6;          // wave id 0..3
    const int x0 = blockIdx.x * TW;
    const int y0 = blockIdx.y * TH;
    const size_t base = (size_t)blockIdx.z * (size_t)(HH * WW);
    const float* imb = im_in + base;
    const float* peb = pe_in + base;

    // Stage raw tile + halo(3) into LDS, zero padding outside the image
    for (int i = tid; i < LH * LW; i += 256) {
        int r = i / LW;
        int c = i - r * LW;
        int gy = y0 - RAD + r;
        int gx = x0 - RAD + c;
        bool ok = ((unsigned)gy < (unsigned)HH) && ((unsigned)gx < (unsigned)WW);
        int gi = gy * WW + gx;
        sI[r][c] = ok ? imb[gi] : 0.0f;
        sP[r][c] = ok ? peb[gi] : 0.0f;
    }
    __syncthreads();

    const float w28 = 1.0f / 28.0f;   // fp32-rounded, as in the ref kernels
    const float w16 = 0.0625f;        // exact
    const v2 w28v = {w28, w28};
    const v2 w16v = {w16, w16};

    const int r0 = wv * RPW;
    // Single LDS address per array; all window reads use immediate offsets.
    const float* pI = &sI[r0][tx];
    const float* pP = &sP[r0][tx];
    float* oI = im_out + base + (size_t)(y0 + r0) * WW + (x0 + tx);
    float* oP = pe_out + base + (size_t)(y0 + r0) * WW + (x0 + tx);

    #pragma unroll 1
    for (int jj = 0; jj < RPW; ++jj) {
        v2 aLR = {0.f, 0.f}, aQN = {0.f, 0.f}, aQS = {0.f, 0.f};
        float U = 0.f, Dd = 0.f;
        v2 qn01, qn23, qN, qs01, qs23, qS, h3;
        float cu01, cu23, cu, cd01, cd23, cd, cP, cI;

        #pragma unroll
        for (int w = 0; w < 7; ++w) {
            // ---- im row w: 7 taps, consumed in col order by each chain ----
            const float* rI = pI + w * LW;
            const float w0 = rI[0], w1 = rI[1], w2 = rI[2], w3 = rI[3],
                        w4 = rI[4], w5 = rI[5], w6 = rI[6];
            const v2 p0 = {w0, w3}, p1 = {w1, w4}, p2 = {w2, w5}, p3 = {w3, w6};

            aLR = __builtin_elementwise_fma(p0, w28v, aLR);   // L cols0-3 | R cols3-6
            aLR = __builtin_elementwise_fma(p1, w28v, aLR);
            aLR = __builtin_elementwise_fma(p2, w28v, aLR);
            aLR = __builtin_elementwise_fma(p3, w28v, aLR);
            if (w < 4) {
                U = fmaf(w0, w28, U);  U = fmaf(w1, w28, U);  U = fmaf(w2, w28, U);
                U = fmaf(w3, w28, U);  U = fmaf(w4, w28, U);  U = fmaf(w5, w28, U);
                U = fmaf(w6, w28, U);
                aQN = __builtin_elementwise_fma(p0, w16v, aQN);
                aQN = __builtin_elementwise_fma(p1, w16v, aQN);
                aQN = __builtin_elementwise_fma(p2, w16v, aQN);
                aQN = __builtin_elementwise_fma(p3, w16v, aQN);
            }
            if (w >= 3) {
                Dd = fmaf(w0, w28, Dd); Dd = fmaf(w1, w28, Dd); Dd = fmaf(w2, w28, Dd);
                Dd = fmaf(w3, w28, Dd); Dd = fmaf(w4, w28, Dd); Dd = fmaf(w5, w28, Dd);
                Dd = fmaf(w6, w28, Dd);
                aQS = __builtin_elementwise_fma(p0, w16v, aQS);
                aQS = __builtin_elementwise_fma(p1, w16v, aQS);
                aQS = __builtin_elementwise_fma(p2, w16v, aQS);
                aQS = __builtin_elementwise_fma(p3, w16v, aQS);
            }
            if (w == 3) cI = w3;      // window center

            // ---- pert row w: partials, exact pairwise trees ----
            const float* rP = pP + w * LW;
            const float b0 = rP[0], b1 = rP[1], b2 = rP[2], b3 = rP[3],
                        b4 = rP[4], b5 = rP[5], b6 = rP[6];
            const v2 h = {(b0 + b1) + (b2 + b3), (b3 + b4) + (b5 + b6)};
            const float c = b3;
            if (w == 0) { qn01 = h;              cu01 = c; }
            if (w == 1) { qn01 = qn01 + h;       cu01 = cu01 + c; }
            if (w == 2) { qn23 = h;              cu23 = c; }
            if (w == 3) { qn23 = qn23 + h;       cu23 = cu23 + c;
                          qN = qn01 + qn23;      cu = cu01 + cu23;
                          h3 = h; cP = c;
                          qs01 = h;              cd01 = c; }
            if (w == 4) { qs01 = qs01 + h;       cd01 = cd01 + c; }
            if (w == 5) { qs23 = h;              cd23 = c; }
            if (w == 6) { qs23 = qs23 + h;       cd23 = cd23 + c;
                          qS = qs01 + qs23;      cd = cd01 + cd23; }
        }

        // ---- epilogue (identical to R4) ----
        const v2 cI2 = {cI, cI};
        const v2 d01 = aLR - cI2;
        const float d2 = U - cI, d3 = Dd - cI;
        const v2 d45 = aQN - cI2;
        const v2 d67 = aQS - cI2;
        float d[8] = {d01.x, d01.y, d2, d3, d45.x, d45.y, d67.x, d67.y};

        float e[8];
        {
            const v2 cP2 = {cP, cP};
            v2 eLR = (qN + qS - h3) * w28v - cP2;   // (L, R)
            v2 eQN = qN * w16v - cP2;               // (NW, NE)
            v2 eQS = qS * w16v - cP2;               // (SW, SE)
            e[0] = eLR.x;  e[1] = eLR.y;
            e[2] = (qN.x + qN.y - cu) * w28 - cP;   // U
            e[3] = (qS.x + qS.y - cd) * w28 - cP;   // D
            e[4] = eQN.x;  e[5] = eQN.y;
            e[6] = eQS.x;  e[7] = eQS.y;
        }

        // first-index-wins argmin over |d| (jnp.argmin tie-break)
        float bestAbs = fabsf(d[0]);
        float bd = d[0];
        float be = e[0];
        #pragma unroll
        for (int j = 1; j < 8; ++j) {
            float a = fabsf(d[j]);
            bool take = a < bestAbs;
            bestAbs = take ? a : bestAbs;
            bd = take ? d[j] : bd;
            be = take ? e[j] : be;
        }

        if (storeIm) *oI = cI + bd;   // bit-exact im chain
        *oP = cP + be;

        pI += LW;  pP += LW;  oI += WW;  oP += WW;
    }
}

extern "C" void kernel_launch(void* const* d_in, const int* in_sizes, int n_in,
                              void* d_out, int out_size, void* d_ws, size_t ws_size,
                              hipStream_t stream) {
    const float* im0 = (const float*)d_in[0];
    const float* pe0 = (const float*)d_in[1];
    float* out = (float*)d_out;

    const size_t npix = (size_t)NIMG * HH * WW;   // 3,145,728
    float* imA = (float*)d_ws;                    // 12.6 MB
    float* imB = imA + npix;                      // 12.6 MB
    float* peA = imB + npix;                      // 12.6 MB (ws total 37.7 MB)
    float* peB = out;  // d_out doubles as the second pert buffer; parity
                       // lands the final (iter-5) pert write in d_out.

    dim3 grid(WW / TW, HH / TH, NIMG);            // 8 x 32 x 12 = 3072 blocks
    dim3 block(256);

    swf_step<<<grid, block, 0, stream>>>(im0, pe0, imA, peA, 1);  // iter 0
    swf_step<<<grid, block, 0, stream>>>(imA, peA, imB, peB, 1);  // iter 1
    swf_step<<<grid, block, 0, stream>>>(imB, peB, imA, peA, 1);  // iter 2
    swf_step<<<grid, block, 0, stream>>>(imA, peA, imB, peB, 1);  // iter 3
    swf_step<<<grid, block, 0, stream>>>(imB, peB, imA, peA, 1);  // iter 4
    // iter 5: im store is dead (result = filtered pert only) -> skip
    swf_step<<<grid, block, 0, stream>>>(imA, peA, imB, out, 0);  // iter 5
}

// Round 6
// 252.263 us; speedup vs baseline: 1.4388x; 1.4388x over previous
//
#include <hip/hip_runtime.h>

#define HH 512
#define WW 512
#define NIMG 12
#define RAD 3
#define TW 64
#define TH 16
#define LW (TW + 2*RAD)   // 70
#define LH (TH + 2*RAD)   // 22
#define RPW 4             // output rows per wave (TH / 4 waves)

typedef float v2 __attribute__((ext_vector_type(2)));

// R6: streaming window, NO launch_bounds clamp.
//
// SESSION LEDGER:
//  R1 fuse2 48KB LDS: 256us. Occ 18.6, busy 55 -> latency-bound.
//  R2 fuse2 + bounds(256,4): 554us. VGPR clamped to 64 < ring's ~90 ->
//     scratch spill (WRITE 380MB/disp).
//  R3 fuse2 TH=16: 276us. VGPR tier pins waves/SIMD regardless of LDS.
//  R4 unfused + pi-pair ring: 225.5us (best). pk_fma_f32 is half-rate on
//     gfx950 -> packing removes movs only. ~45% stall at 92 VGPR.
//  R5 streaming + bounds(256,8): 363us. Clamp drove VGPR to 32 ->
//     spill AGAIN (WRITE 132MB). Occupancy 63% proved residency rises;
//     spill ate the gain. Lesson: never clamp below the live set --
//     instead make the natural live set fit the tier.
//  R6: same streaming body (live set ~55 regs by hand count), no clamp,
//     + live-state trims (flat LDS indices, per-row store-index
//     recompute). Target: natural VGPR <= 64 -> 8 waves/SIMD, no spill.
//
// NUMERICS CONTRACT (harness-validated through R5, absmax 9.77e-4):
//  - conv = sequential fma over the 7x7 window, (ky,kx) row-major, one
//    accumulator per direction; im path bit-exact vs the fp32 ref replay.
//  - Streaming preserves every chain's tap order exactly:
//      L/R: rows 0..6, pairs {w[d],w[d+3]} d=0..3     (packed lanes L,R)
//      U:   rows 0..3, cols 0..6 scalar               D: rows 3..6
//      NW/NE: rows 0..3, same pairs (packed)          SW/SE: rows 3..6
//  - pert quadrant trees identical to R4/R5:
//      qN=(h0+h1)+(h2+h3), qS=(h3+h4)+(h5+h6), cu/cd likewise.
__global__ __launch_bounds__(256) void swf_step(
    const float* __restrict__ im_in, const float* __restrict__ pe_in,
    float* __restrict__ im_out, float* __restrict__ pe_out, int storeIm)
{
    __shared__ float sI[LH * LW];
    __shared__ float sP[LH * LW];

    const int tid = threadIdx.x;
    const int tx = tid & 63;
    const int wv = tid >> 6;          // wave id 0..3
    const int x0 = blockIdx.x * TW;
    const int y0 = blockIdx.y * TH;
    const size_t base = (size_t)blockIdx.z * (size_t)(HH * WW);
    const float* imb = im_in + base;
    const float* peb = pe_in + base;

    // Stage raw tile + halo(3) into LDS, zero padding outside the image
    for (int i = tid; i < LH * LW; i += 256) {
        int r = i / LW;
        int c = i - r * LW;
        int gy = y0 - RAD + r;
        int gx = x0 - RAD + c;
        bool ok = ((unsigned)gy < (unsigned)HH) && ((unsigned)gx < (unsigned)WW);
        int gi = gy * WW + gx;
        sI[i] = ok ? imb[gi] : 0.0f;
        sP[i] = ok ? peb[gi] : 0.0f;
    }
    __syncthreads();

    const float w28 = 1.0f / 28.0f;   // fp32-rounded, as in the ref kernels
    const float w16 = 0.0625f;        // exact
    const v2 w28v = {w28, w28};
    const v2 w16v = {w16, w16};

    const int r0 = wv * RPW;
    int ls = r0 * LW + tx;            // flat 32-bit LDS index (row r0, col tx)

    #pragma unroll 1
    for (int jj = 0; jj < RPW; ++jj) {
        v2 aLR = {0.f, 0.f}, aQN = {0.f, 0.f}, aQS = {0.f, 0.f};
        float U = 0.f, Dd = 0.f;
        v2 qn01, qn23, qN, qs01, qs23, qS, h3;
        float cu01, cu23, cu, cd01, cd23, cd, cP, cI;

        #pragma unroll
        for (int w = 0; w < 7; ++w) {
            // ---- im row w: 7 taps, consumed in col order by each chain ----
            const int ri = ls + w * LW;
            const float w0 = sI[ri],     w1 = sI[ri + 1], w2 = sI[ri + 2],
                        w3 = sI[ri + 3], w4 = sI[ri + 4], w5 = sI[ri + 5],
                        w6 = sI[ri + 6];
            const v2 p0 = {w0, w3}, p1 = {w1, w4}, p2 = {w2, w5}, p3 = {w3, w6};

            aLR = __builtin_elementwise_fma(p0, w28v, aLR);   // L cols0-3 | R cols3-6
            aLR = __builtin_elementwise_fma(p1, w28v, aLR);
            aLR = __builtin_elementwise_fma(p2, w28v, aLR);
            aLR = __builtin_elementwise_fma(p3, w28v, aLR);
            if (w < 4) {
                U = fmaf(w0, w28, U);  U = fmaf(w1, w28, U);  U = fmaf(w2, w28, U);
                U = fmaf(w3, w28, U);  U = fmaf(w4, w28, U);  U = fmaf(w5, w28, U);
                U = fmaf(w6, w28, U);
                aQN = __builtin_elementwise_fma(p0, w16v, aQN);
                aQN = __builtin_elementwise_fma(p1, w16v, aQN);
                aQN = __builtin_elementwise_fma(p2, w16v, aQN);
                aQN = __builtin_elementwise_fma(p3, w16v, aQN);
            }
            if (w >= 3) {
                Dd = fmaf(w0, w28, Dd); Dd = fmaf(w1, w28, Dd); Dd = fmaf(w2, w28, Dd);
                Dd = fmaf(w3, w28, Dd); Dd = fmaf(w4, w28, Dd); Dd = fmaf(w5, w28, Dd);
                Dd = fmaf(w6, w28, Dd);
                aQS = __builtin_elementwise_fma(p0, w16v, aQS);
                aQS = __builtin_elementwise_fma(p1, w16v, aQS);
                aQS = __builtin_elementwise_fma(p2, w16v, aQS);
                aQS = __builtin_elementwise_fma(p3, w16v, aQS);
            }
            if (w == 3) cI = w3;      // window center

            // ---- pert row w: partials, exact pairwise trees ----
            const float b0 = sP[ri],     b1 = sP[ri + 1], b2 = sP[ri + 2],
                        b3 = sP[ri + 3], b4 = sP[ri + 4], b5 = sP[ri + 5],
                        b6 = sP[ri + 6];
            const v2 h = {(b0 + b1) + (b2 + b3), (b3 + b4) + (b5 + b6)};
            const float c = b3;
            if (w == 0) { qn01 = h;              cu01 = c; }
            if (w == 1) { qn01 = qn01 + h;       cu01 = cu01 + c; }
            if (w == 2) { qn23 = h;              cu23 = c; }
            if (w == 3) { qn23 = qn23 + h;       cu23 = cu23 + c;
                          qN = qn01 + qn23;      cu = cu01 + cu23;
                          h3 = h; cP = c;
                          qs01 = h;              cd01 = c; }
            if (w == 4) { qs01 = qs01 + h;       cd01 = cd01 + c; }
            if (w == 5) { qs23 = h;              cd23 = c; }
            if (w == 6) { qs23 = qs23 + h;       cd23 = cd23 + c;
                          qS = qs01 + qs23;      cd = cd01 + cd23; }
        }

        // ---- epilogue (identical to R4/R5) ----
        const v2 cI2 = {cI, cI};
        const v2 d01 = aLR - cI2;
        const float d2 = U - cI, d3 = Dd - cI;
        const v2 d45 = aQN - cI2;
        const v2 d67 = aQS - cI2;
        float d[8] = {d01.x, d01.y, d2, d3, d45.x, d45.y, d67.x, d67.y};

        float e[8];
        {
            const v2 cP2 = {cP, cP};
            v2 eLR = (qN + qS - h3) * w28v - cP2;   // (L, R)
            v2 eQN = qN * w16v - cP2;               // (NW, NE)
            v2 eQS = qS * w16v - cP2;               // (SW, SE)
            e[0] = eLR.x;  e[1] = eLR.y;
            e[2] = (qN.x + qN.y - cu) * w28 - cP;   // U
            e[3] = (qS.x + qS.y - cd) * w28 - cP;   // D
            e[4] = eQN.x;  e[5] = eQN.y;
            e[6] = eQS.x;  e[7] = eQS.y;
        }

        // first-index-wins argmin over |d| (jnp.argmin tie-break)
        float bestAbs = fabsf(d[0]);
        float bd = d[0];
        float be = e[0];
        #pragma unroll
        for (int j = 1; j < 8; ++j) {
            float a = fabsf(d[j]);
            bool take = a < bestAbs;
            bestAbs = take ? a : bestAbs;
            bd = take ? d[j] : bd;
            be = take ? e[j] : be;
        }

        // store index recomputed per row: no 64-bit pointers live in-loop
        const size_t gi = base + (size_t)(y0 + r0 + jj) * WW + (x0 + tx);
        if (storeIm) im_out[gi] = cI + bd;   // bit-exact im chain
        pe_out[gi] = cP + be;

        ls += LW;
    }
}

extern "C" void kernel_launch(void* const* d_in, const int* in_sizes, int n_in,
                              void* d_out, int out_size, void* d_ws, size_t ws_size,
                              hipStream_t stream) {
    const float* im0 = (const float*)d_in[0];
    const float* pe0 = (const float*)d_in[1];
    float* out = (float*)d_out;

    const size_t npix = (size_t)NIMG * HH * WW;   // 3,145,728
    float* imA = (float*)d_ws;                    // 12.6 MB
    float* imB = imA + npix;                      // 12.6 MB
    float* peA = imB + npix;                      // 12.6 MB (ws total 37.7 MB)
    float* peB = out;  // d_out doubles as the second pert buffer; parity
                       // lands the final (iter-5) pert write in d_out.

    dim3 grid(WW / TW, HH / TH, NIMG);            // 8 x 32 x 12 = 3072 blocks
    dim3 block(256);

    swf_step<<<grid, block, 0, stream>>>(im0, pe0, imA, peA, 1);  // iter 0
    swf_step<<<grid, block, 0, stream>>>(imA, peA, imB, peB, 1);  // iter 1
    swf_step<<<grid, block, 0, stream>>>(imB, peB, imA, peA, 1);  // iter 2
    swf_step<<<grid, block, 0, stream>>>(imA, peA, imB, peB, 1);  // iter 3
    swf_step<<<grid, block, 0, stream>>>(imB, peB, imA, peA, 1);  // iter 4
    // iter 5: im store is dead (result = filtered pert only) -> skip
    swf_step<<<grid, block, 0, stream>>>(imA, peA, imB, out, 0);  // iter 5
}